// Round 5
// baseline (364.299 us; speedup 1.0000x reference)
//
#include <hip/hip_runtime.h>

// CfCHead: B=64, S=2048, H=1024 sequential nonlinear scan. Round-5:
// full producer/helper pipeline. 256 blocks x 512 threads.
//  - waves 0-3 (producers): recurrence ONLY, gates read from LDS into regs.
//    ~12 VALU + 2 transcendentals per step on the critical wave.
//  - waves 4-7 (helpers): generate gates for chunk k+1 (3x HW exp2 +
//    2 sigmoid polys, x-only, full ILP) into a double-buffered LDS queue,
//    and reduce the projection of chunk k-1's h. One barrier per chunk.
//  - scalar math identical to verified round-4 recurrence: multiplicative
//    En=e^{-n} update (cubic e^delta Taylor), sigmoid polys for g/lambda,
//    exp2(C)+rcp for sigmoid(c) (unbounded arg).
//  - all LDS rows stride 9 (odd): b128 conflict-free, b32 2-way (free).

#define Bv   64
#define Sv   2048
#define Hv   1024
#define TPB  256
#define NT   512
#define CH   8
#define NCH  (Sv / CH)    // 256 chunks
#define GSTR 9            // row stride (in float4s for gates, floats for il/h)

#define NL2E (-1.44269504088896340736f)
#define KNU   0.014426950408889634f     /* 0.01*L2E */

__device__ __forceinline__ float fexp2(float x) { return __builtin_amdgcn_exp2f(x); }
__device__ __forceinline__ float frcp(float x)  { return __builtin_amdgcn_rcpf(x); }

// scale*sigmoid(z) = A + z*Q(z^2), deg-9 odd, coeffs pre-scaled (verified r4)
__device__ __forceinline__ float sig_poly(float z, float q4, float q3, float q2,
                                          float q1, float q0, float A) {
    const float w = z * z;
    float Q = fmaf(w, q4, q3);
    Q = fmaf(Q, w, q2);
    Q = fmaf(Q, w, q1);
    Q = fmaf(Q, w, q0);
    return fmaf(z, Q, A);
}

// out[b*S*2 + t*2 + k] = proj_b[k]  (clears 0xAA poison; scan atomically adds)
__global__ __launch_bounds__(256) void init_out(const float* __restrict__ proj_b,
                                                float* __restrict__ out) {
    int i = blockIdx.x * 256 + threadIdx.x;
    out[i] = proj_b[i & 1];
}

__global__ __launch_bounds__(NT, 1) void cfc_scan(
    const float* __restrict__ x_codes,
    const float* __restrict__ Wi_w, const float* __restrict__ Wi_b,
    const float* __restrict__ Wf_w, const float* __restrict__ Wf_b,
    const float* __restrict__ Wo_w, const float* __restrict__ Wo_b,
    const float* __restrict__ Wg_w, const float* __restrict__ Wg_b,
    const float* __restrict__ Wl_w, const float* __restrict__ Wl_b,
    const float* __restrict__ proj_w,
    const float* __restrict__ n_init,
    float* __restrict__ out)
{
    // gate queue {Gf, GiGg, Go, Gs} + Il + h, double-buffered
    __shared__ float4 glds[2][TPB * GSTR];   // 73728 B
    __shared__ float  illds[2][TPB * GSTR];  //  9216 B
    __shared__ float  hlds[2][TPB * GSTR];   //  9216 B

    const int b   = blockIdx.x >> 2;
    const int q   = blockIdx.x & 3;
    const int tid = threadIdx.x;
    const int ct  = tid - TPB;               // helper-local id

    const float* __restrict__ xrow = x_codes + b * Sv;
    float* __restrict__ orow = out + b * (Sv * 2);

    // ---- producer state ----
    float En = 0.f, C = 0.f, h = 0.f;
    if (tid < TPB) {
        En = fexp2(n_init[q * TPB + tid] * NL2E);   // e^{-n_0}
    }

    // ---- helper setup: folded weights + reduce pattern ----
    float wi2 = 0, bi2 = 0, wf2 = 0, bf2 = 0, wo2 = 0, bo2 = 0;
    float wgp = 0, bgp = 0, wlp = 0, blp = 0;
    int   offs[16];                    // LDS float-offsets for reduce reads
    float pwreg[16];                   // matching proj_w values
    int rk = 0, rt = 0, rseg = 0;
    if (tid >= TPB) {
        const int j = q * TPB + ct;
        const float wi = Wi_w[j], bi = Wi_b[j];
        const float wf = Wf_w[j], bf = Wf_b[j];
        const float wo = Wo_w[j], bo = Wo_b[j];
        const float wg = Wg_w[j], bg = Wg_b[j];
        const float wl = Wl_w[j], bl = Wl_b[j];
        // exp args in log2 domain: arg = code*(w*0.01*L2E) + (b-0.65w)*L2E
        wi2 = wi * KNU;   bi2 = fmaf(-0.65f, wi, bi) * -NL2E;
        wf2 = wf * KNU;   bf2 = fmaf(-0.65f, wf, bf) * -NL2E;
        wo2 = wo * KNU;   bo2 = fmaf(-0.65f, wo, bo) * -NL2E;
        // sigmoid args in natural domain
        wgp = wg * 0.01f; bgp = fmaf(-0.65f, wg, bg);
        wlp = wl * 0.01f; blp = fmaf(-0.65f, wl, bl);
        // reduce mapping: ct = rk*128 + rt*16 + rseg
        rk   = ct >> 7;
        rt   = (ct >> 4) & 7;
        rseg = ct & 15;
        const float* __restrict__ pwsrc = proj_w + rk * Hv + q * TPB;
        #pragma unroll
        for (int i2 = 0; i2 < 16; ++i2) {
            const int jj = rseg * 16 + ((i2 + rseg) & 15);  // rotated: spread banks
            offs[i2]  = jj * GSTR + rt;
            pwreg[i2] = pwsrc[jj];
        }
        // ---- prologue: generate gates for chunk 0 into buffer 0 ----
        float4* __restrict__ gw = &glds[0][ct * GSTR];
        float*  __restrict__ iw = &illds[0][ct * GSTR];
        #pragma unroll
        for (int u = 0; u < CH; ++u) {
            const float xc = xrow[u];
            const float Gi = fexp2(fmaf(xc, wi2, bi2));
            const float Gf = fexp2(fmaf(xc, wf2, bf2));
            const float Go = fexp2(fmaf(xc, wo2, bo2));
            const float sg = sig_poly(fmaf(xc, wgp, bgp),
                                      -3.0811453e-5f, 3.0414935e-4f,
                                      -3.0056147e-3f, 3.0056147e-2f,
                                      -0.36067376f, -0.72134752f);  // -L2E*sig
            const float tl = sig_poly(fmaf(xc, wlp, blp),
                                      2.1356902e-7f, -2.1081349e-6f,
                                      2.0833333e-5f, -2.0833333e-4f,
                                      2.5e-3f, 5.0e-3f);            // 0.01*sig
            gw[u] = make_float4(Gf, Gi * sg, Go, (Gi + Gf) + Go);
            iw[u] = fmaf(tl - 1.0f, tl, 1.0f);                      // 1/(1+tl)
        }
    }
    __syncthreads();

    int par = 0;
    for (int ci = 0; ci < NCH; ++ci, par ^= 1) {
        if (tid < TPB) {
            // ---- producer: recurrence for chunk ci from glds[par] ----
            const float4* __restrict__ gr = &glds[par][tid * GSTR];
            const float*  __restrict__ ir = &illds[par][tid * GSTR];
            float4 g[CH]; float il[CH];
            #pragma unroll
            for (int u = 0; u < CH; ++u) { g[u] = gr[u]; il[u] = ir[u]; }
            float* __restrict__ hw = &hlds[par][tid * GSTR];
            #pragma unroll
            for (int u = 0; u < CH; ++u) {
                const float ef = g[u].x * En;                    // f_t
                C = fmaf(ef, C, g[u].y * En);                    // C = -L2E*c
                const float e2C  = fexp2(C);                     // e^{-c}
                const float sc01 = frcp(fmaf(e2C, 100.f, 100.f)); // 0.01*sig(c)
                h = fmaf(g[u].z * En, sc01, h) * il[u];
                hw[u] = h;
                // En *= e^{d}, d = 0.03 - 0.01*(i+f+o); cubic Taylor
                const float d = fmaf(g[u].w * En, -0.01f, 0.03f);
                float p = fmaf(d, 0.16666667f, 0.5f);
                p = fmaf(d, p, 1.0f);
                p = fmaf(d, p, 1.0f);
                En *= p;
            }
        } else {
            // ---- helper: gates for chunk ci+1 into glds[par^1] ----
            const int t1 = (ci + 1) * CH;
            if (t1 < Sv) {
                float4* __restrict__ gw = &glds[par ^ 1][ct * GSTR];
                float*  __restrict__ iw = &illds[par ^ 1][ct * GSTR];
                #pragma unroll
                for (int u = 0; u < CH; ++u) {
                    const float xc = xrow[t1 + u];
                    const float Gi = fexp2(fmaf(xc, wi2, bi2));
                    const float Gf = fexp2(fmaf(xc, wf2, bf2));
                    const float Go = fexp2(fmaf(xc, wo2, bo2));
                    const float sg = sig_poly(fmaf(xc, wgp, bgp),
                                              -3.0811453e-5f, 3.0414935e-4f,
                                              -3.0056147e-3f, 3.0056147e-2f,
                                              -0.36067376f, -0.72134752f);
                    const float tl = sig_poly(fmaf(xc, wlp, blp),
                                              2.1356902e-7f, -2.1081349e-6f,
                                              2.0833333e-5f, -2.0833333e-4f,
                                              2.5e-3f, 5.0e-3f);
                    gw[u] = make_float4(Gf, Gi * sg, Go, (Gi + Gf) + Go);
                    iw[u] = fmaf(tl - 1.0f, tl, 1.0f);
                }
            }
            // ---- helper: reduce chunk ci-1's h from hlds[par^1] ----
            if (ci > 0) {
                const float* __restrict__ hb = &hlds[par ^ 1][0];
                float sum = 0.0f;
                #pragma unroll
                for (int i2 = 0; i2 < 16; ++i2)
                    sum = fmaf(hb[offs[i2]], pwreg[i2], sum);
                sum += __shfl_xor(sum, 1, 64);
                sum += __shfl_xor(sum, 2, 64);
                sum += __shfl_xor(sum, 4, 64);
                sum += __shfl_xor(sum, 8, 64);
                if (rseg == 0)
                    atomicAdd(&orow[((ci - 1) * CH + rt) * 2 + rk], sum);
            }
        }
        __syncthreads();
    }

    // ---- epilogue: reduce the final chunk (NCH-1), sitting in hlds[par^1] ----
    if (tid >= TPB) {
        const float* __restrict__ hb = &hlds[par ^ 1][0];
        float sum = 0.0f;
        #pragma unroll
        for (int i2 = 0; i2 < 16; ++i2)
            sum = fmaf(hb[offs[i2]], pwreg[i2], sum);
        sum += __shfl_xor(sum, 1, 64);
        sum += __shfl_xor(sum, 2, 64);
        sum += __shfl_xor(sum, 4, 64);
        sum += __shfl_xor(sum, 8, 64);
        if (rseg == 0)
            atomicAdd(&orow[((NCH - 1) * CH + rt) * 2 + rk], sum);
    }
}

extern "C" void kernel_launch(void* const* d_in, const int* in_sizes, int n_in,
                              void* d_out, int out_size, void* d_ws, size_t ws_size,
                              hipStream_t stream) {
    const float* x_codes = (const float*)d_in[0];
    const float* Wi_w = (const float*)d_in[1];
    const float* Wi_b = (const float*)d_in[2];
    const float* Wf_w = (const float*)d_in[3];
    const float* Wf_b = (const float*)d_in[4];
    const float* Wo_w = (const float*)d_in[5];
    const float* Wo_b = (const float*)d_in[6];
    const float* Wg_w = (const float*)d_in[7];
    const float* Wg_b = (const float*)d_in[8];
    const float* Wl_w = (const float*)d_in[9];
    const float* Wl_b = (const float*)d_in[10];
    const float* proj_w = (const float*)d_in[11];
    const float* proj_b = (const float*)d_in[12];
    const float* n_init = (const float*)d_in[13];
    float* out = (float*)d_out;

    init_out<<<out_size / 256, 256, 0, stream>>>(proj_b, out);
    cfc_scan<<<Bv * (Hv / TPB), NT, 0, stream>>>(
        x_codes, Wi_w, Wi_b, Wf_w, Wf_b, Wo_w, Wo_b, Wg_w, Wg_b, Wl_w, Wl_b,
        proj_w, n_init, out);
}

// Round 6
// 298.923 us; speedup vs baseline: 1.2187x; 1.2187x over previous
//
#include <hip/hip_runtime.h>

// CfCHead: B=64, S=2048, H=1024 sequential nonlinear scan. Round-6:
// round-3 skeleton (best-measured: single producer wave keeps gates in
// registers, helper waves only reduce; 1 barrier/chunk, 0 conflicts)
// + transcendental-count reduction (10 -> 5 per step):
//  - sigmoid(g), sigmoid(lambda): odd deg-9 polys (args bounded |z|<=1.2),
//    coeffs verified in r4/r5 (absmax 0.0078)
//  - En = e^{-n} tracked multiplicatively via cubic e^delta Taylor
//    (kills exp2(m)); only exp2(C) + rcp remain state-dependent
//  - consumer proj_w preloaded to registers (r4 consumer, 0 conflicts)
// KEY LESSON (r5): producer/helper waves share SIMD issue ports - only
// total issue-cycles per chain-step matters. Keep gates in registers.

#define Bv   64
#define Sv   2048
#define Hv   1024
#define TPB  256
#define NT   512
#define CH   16
#define HSTR 17
#define HBUF (TPB * HSTR)

#define NL2E (-1.44269504088896340736f)
#define KNU   0.014426950408889634f     /* 0.01*log2(e) */
#define L2E   1.44269504088896340736f

__device__ __forceinline__ float fexp2(float x) { return __builtin_amdgcn_exp2f(x); }
__device__ __forceinline__ float frcp(float x)  { return __builtin_amdgcn_rcpf(x); }

// scale*sigmoid(z) = A + z*Q(z^2), deg-9 odd, coeffs pre-scaled (verified r4/r5)
__device__ __forceinline__ float sig_poly(float z, float q4, float q3, float q2,
                                          float q1, float q0, float A) {
    const float w = z * z;
    float Q = fmaf(w, q4, q3);
    Q = fmaf(Q, w, q2);
    Q = fmaf(Q, w, q1);
    Q = fmaf(Q, w, q0);
    return fmaf(z, Q, A);
}

// out[b*S*2 + t*2 + k] = proj_b[k]  (clears 0xAA poison; scan atomically adds)
__global__ __launch_bounds__(256) void init_out(const float* __restrict__ proj_b,
                                                float* __restrict__ out) {
    int i = blockIdx.x * 256 + threadIdx.x;
    out[i] = proj_b[i & 1];
}

__global__ __launch_bounds__(NT, 1) void cfc_scan(
    const float* __restrict__ x_codes,
    const float* __restrict__ Wi_w, const float* __restrict__ Wi_b,
    const float* __restrict__ Wf_w, const float* __restrict__ Wf_b,
    const float* __restrict__ Wo_w, const float* __restrict__ Wo_b,
    const float* __restrict__ Wg_w, const float* __restrict__ Wg_b,
    const float* __restrict__ Wl_w, const float* __restrict__ Wl_b,
    const float* __restrict__ proj_w,
    const float* __restrict__ n_init,
    float* __restrict__ out)
{
    __shared__ float hlds[2 * HBUF];    // double-buffered raw h, [par][j][u]

    const int b   = blockIdx.x >> 2;
    const int q   = blockIdx.x & 3;
    const int tid = threadIdx.x;

    const float* __restrict__ xrow = x_codes + b * Sv;
    float* __restrict__ orow = out + b * (Sv * 2);

    // ---- consumer setup (waves 4-7): preload proj_w pattern to registers ----
    const int ct   = tid - TPB;
    const int rk   = (ct >> 7) & 1;
    const int rt   = (ct >> 3) & 15;
    const int rseg = ct & 7;
    float pwreg[32];
    if (tid >= TPB) {
        const float* __restrict__ pwsrc = proj_w + rk * Hv + q * TPB;
        #pragma unroll
        for (int i2 = 0; i2 < 32; ++i2) {
            const int jj = rseg * 32 + ((i2 + 4 * rseg) & 31);
            pwreg[i2] = pwsrc[jj];
        }
    }

    // ---- producer setup (waves 0-3): fold affine maps into weights ----
    float wi2 = 0, bi2 = 0, wf2 = 0, bf2 = 0, wo2 = 0, bo2 = 0;
    float wgp = 0, bgp = 0, wlp = 0, blp = 0;
    float En = 0.f, C = 0.f, h = 0.f;
    if (tid < TPB) {
        const int j = q * TPB + tid;
        const float wi = Wi_w[j], bi = Wi_b[j];
        const float wf = Wf_w[j], bf = Wf_b[j];
        const float wo = Wo_w[j], bo = Wo_b[j];
        const float wg = Wg_w[j], bg = Wg_b[j];
        const float wl = Wl_w[j], bl = Wl_b[j];
        // exp args in log2 domain: arg = code*(w*0.01*L2E) + (b-0.65w)*L2E
        wi2 = wi * KNU;   bi2 = fmaf(-0.65f, wi, bi) * L2E;
        wf2 = wf * KNU;   bf2 = fmaf(-0.65f, wf, bf) * L2E;
        wo2 = wo * KNU;   bo2 = fmaf(-0.65f, wo, bo) * L2E;
        // sigmoid args in natural domain: z = code*(w*0.01) + (b-0.65w)
        wgp = wg * 0.01f; bgp = fmaf(-0.65f, wg, bg);
        wlp = wl * 0.01f; blp = fmaf(-0.65f, wl, bl);
        En = fexp2(n_init[j] * NL2E);   // e^{-n_0}
    }

    float Gf[CH], GiGg[CH], Go[CH], Gs[CH], Il[CH];

    int par = 0;
    for (int t0 = 0; t0 < Sv; t0 += CH, par ^= 1) {
        if (tid < TPB) {
            // -- x-only gates: 3 HW exp2 + 2 polys per step, full ILP --
            #pragma unroll
            for (int u = 0; u < CH; ++u) {
                const float xc = xrow[t0 + u];
                const float Gi = fexp2(fmaf(xc, wi2, bi2));     // e^{pre_i}
                Gf[u] = fexp2(fmaf(xc, wf2, bf2));              // e^{pre_f}
                Go[u] = fexp2(fmaf(xc, wo2, bo2));              // e^{pre_o}
                // -L2E * sigmoid(pre_g)
                const float sg = sig_poly(fmaf(xc, wgp, bgp),
                                          -3.0811453e-5f, 3.0414935e-4f,
                                          -3.0056147e-3f, 3.0056147e-2f,
                                          -0.36067376f, -0.72134752f);
                // 0.01 * sigmoid(pre_l)
                const float tl = sig_poly(fmaf(xc, wlp, blp),
                                          2.1356902e-7f, -2.1081349e-6f,
                                          2.0833333e-5f, -2.0833333e-4f,
                                          2.5e-3f, 5.0e-3f);
                GiGg[u] = Gi * sg;
                Gs[u]   = (Gi + Gf[u]) + Go[u];
                Il[u]   = fmaf(tl - 1.0f, tl, 1.0f);            // 1/(1+tl)
            }
            // -- serial recurrence: exp2(C) + rcp only; multiplicative En --
            float* __restrict__ hrow = &hlds[par * HBUF + tid * HSTR];
            #pragma unroll
            for (int u = 0; u < CH; ++u) {
                const float ef = Gf[u] * En;                      // f_t
                C = fmaf(ef, C, GiGg[u] * En);                    // C = -L2E*c
                const float e2C  = fexp2(C);                      // e^{-c}
                const float sc01 = frcp(fmaf(e2C, 100.f, 100.f)); // .01*sig(c)
                h = fmaf(Go[u] * En, sc01, h) * Il[u];
                hrow[u] = h;
                // En *= e^{d}, d = 0.03 - 0.01*(i+f+o); cubic Taylor
                const float d = fmaf(Gs[u] * En, -0.01f, 0.03f);
                float p = fmaf(d, 0.16666667f, 0.5f);
                p = fmaf(d, p, 1.0f);
                p = fmaf(d, p, 1.0f);
                En *= p;
            }
        }
        __syncthreads();   // producers publish h[par]; consumers reduce it
        if (tid >= TPB) {
            const float* __restrict__ hb = &hlds[par * HBUF];
            float sum = 0.0f;
            #pragma unroll
            for (int i2 = 0; i2 < 32; ++i2) {
                const int jj = rseg * 32 + ((i2 + 4 * rseg) & 31); // 2-way banks
                sum = fmaf(hb[jj * HSTR + rt], pwreg[i2], sum);
            }
            sum += __shfl_xor(sum, 1, 64);
            sum += __shfl_xor(sum, 2, 64);
            sum += __shfl_xor(sum, 4, 64);
            if (rseg == 0) atomicAdd(&orow[(t0 + rt) * 2 + rk], sum);
        }
    }
}

extern "C" void kernel_launch(void* const* d_in, const int* in_sizes, int n_in,
                              void* d_out, int out_size, void* d_ws, size_t ws_size,
                              hipStream_t stream) {
    const float* x_codes = (const float*)d_in[0];
    const float* Wi_w = (const float*)d_in[1];
    const float* Wi_b = (const float*)d_in[2];
    const float* Wf_w = (const float*)d_in[3];
    const float* Wf_b = (const float*)d_in[4];
    const float* Wo_w = (const float*)d_in[5];
    const float* Wo_b = (const float*)d_in[6];
    const float* Wg_w = (const float*)d_in[7];
    const float* Wg_b = (const float*)d_in[8];
    const float* Wl_w = (const float*)d_in[9];
    const float* Wl_b = (const float*)d_in[10];
    const float* proj_w = (const float*)d_in[11];
    const float* proj_b = (const float*)d_in[12];
    const float* n_init = (const float*)d_in[13];
    float* out = (float*)d_out;

    init_out<<<out_size / 256, 256, 0, stream>>>(proj_b, out);
    cfc_scan<<<Bv * (Hv / TPB), NT, 0, stream>>>(
        x_codes, Wi_w, Wi_b, Wf_w, Wf_b, Wo_w, Wo_b, Wg_w, Wg_b, Wl_w, Wl_b,
        proj_w, n_init, out);
}

// Round 7
// 267.381 us; speedup vs baseline: 1.3625x; 1.1180x over previous
//
#include <hip/hip_runtime.h>

// CfCHead: B=64, S=2048, H=1024 sequential nonlinear scan. Round-7:
// round-3 math (verified best: HW exp/rcp everywhere, CUP drift table)
// + explicit cross-chunk software pipeline in REGISTERS:
//   gen(chunk k+1) is textually and data-independently co-scheduled with
//   the serial recurrence of chunk k, so the scheduler can slot ~180
//   independent instructions into the recurrence's latency chain.
//   (r3's fused schedule serialized gate-chain + n-chain every step.)
// Ping-pong register arrays via 2-chunk unroll; 1 barrier/chunk.
// Consumer waves: r6's register-preloaded proj_w reduce (0 conflicts).
// LESSONS ENCODED: r6 - polys lose to HW trans; r5 - helper-wave gate
// transport loses (shared issue ports); r3 - loop fusion is the stall.

#define Bv   64
#define Sv   2048
#define Hv   1024
#define TPB  256
#define NT   512
#define CH   16
#define NCH  (Sv / CH)
#define HSTR 17
#define HBUF (TPB * HSTR)

#define L2E   1.44269504088896340736f
#define NL2E (-1.44269504088896340736f)
#define LN2   0.69314718055994530942f
#define KNU   0.014426950408889634f     /* 0.01*L2E  */
#define CREB  0.692493619626702435f     /* 16*0.03*L2E */
#define LOG2_001 (-6.6438561897747247f) /* log2(0.01) */

__device__ __forceinline__ float fexp2(float x) { return __builtin_amdgcn_exp2f(x); }
__device__ __forceinline__ float frcp(float x)  { return __builtin_amdgcn_rcpf(x); }

// out[b*S*2 + t*2 + k] = proj_b[k]  (clears 0xAA poison; scan atomically adds)
__global__ __launch_bounds__(256) void init_out(const float* __restrict__ proj_b,
                                                float* __restrict__ out) {
    int i = blockIdx.x * 256 + threadIdx.x;
    out[i] = proj_b[i & 1];
}

__global__ __launch_bounds__(NT, 1) void cfc_scan(
    const float* __restrict__ x_codes,
    const float* __restrict__ Wi_w, const float* __restrict__ Wi_b,
    const float* __restrict__ Wf_w, const float* __restrict__ Wf_b,
    const float* __restrict__ Wo_w, const float* __restrict__ Wo_b,
    const float* __restrict__ Wg_w, const float* __restrict__ Wg_b,
    const float* __restrict__ Wl_w, const float* __restrict__ Wl_b,
    const float* __restrict__ proj_w,
    const float* __restrict__ n_init,
    float* __restrict__ out)
{
    __shared__ float hlds[2 * HBUF];    // double-buffered raw h, [par][j][u]

    const int b   = blockIdx.x >> 2;
    const int q   = blockIdx.x & 3;
    const int tid = threadIdx.x;

    const float* __restrict__ xrow = x_codes + b * Sv;
    float* __restrict__ orow = out + b * (Sv * 2);

    // ---- consumer setup (waves 4-7): preload proj_w pattern to registers ----
    const int ct   = tid - TPB;
    const int rk   = (ct >> 7) & 1;
    const int rt   = (ct >> 3) & 15;
    const int rseg = ct & 7;
    float pwreg[32];
    if (tid >= TPB) {
        const float* __restrict__ pwsrc = proj_w + rk * Hv + q * TPB;
        #pragma unroll
        for (int i2 = 0; i2 < 32; ++i2) {
            const int jj = rseg * 32 + ((i2 + 4 * rseg) & 31);
            pwreg[i2] = pwsrc[jj];
        }
    }

    // ---- producer setup (waves 0-3): fold affine maps (r3 verbatim) ----
    float wi2 = 0, bi2 = 0, wf2 = 0, bf2 = 0, wo2 = 0, bo2 = 0;
    float wg2 = 0, bg2 = 0, wl2 = 0, bl2 = 0;
    float m = 0, En = 0, C = 0, h = 0;
    if (tid < TPB) {
        const int j = q * TPB + tid;
        const float wi = Wi_w[j], bi = Wi_b[j];
        const float wf = Wf_w[j], bf = Wf_b[j];
        const float wo = Wo_w[j], bo = Wo_b[j];
        const float wg = Wg_w[j], bg = Wg_b[j];
        const float wl = Wl_w[j], bl = Wl_b[j];
        wi2 = wi * KNU;  bi2 = fmaf(-0.65f, wi, bi) * L2E;
        wf2 = wf * KNU;  bf2 = fmaf(-0.65f, wf, bf) * L2E;
        wo2 = wo * KNU;  bo2 = fmaf(-0.65f, wo, bo) * L2E + LOG2_001;
        wg2 = -wg * KNU; bg2 = fmaf(-0.65f, wg, bg) * NL2E;
        wl2 = -wl * KNU; bl2 = fmaf(-0.65f, wl, bl) * NL2E;
        m  = n_init[j] * NL2E;   // m = -n*L2E
        En = fexp2(m);           // e^{-n}
    }

    // 2^{0.03*L2E*u} = e^{0.03u}: per-step drift of e^{-n} within a chunk
    static const float CUP[CH] = {
        1.0f,        1.03045453f, 1.06183655f, 1.09417428f,
        1.12749685f, 1.16183424f, 1.19721736f, 1.23367806f,
        1.27124915f, 1.30996445f, 1.34985881f, 1.39096813f,
        1.43332941f, 1.47698079f, 1.52196156f, 1.56831219f };

    // x-only gate generation for one chunk (ILP-rich, r3 math verbatim)
    auto gen = [&](int t0, float* Gf, float* GiGg, float* Goa, float* Gs,
                   float* Il) {
        #pragma unroll
        for (int u = 0; u < CH; ++u) {
            const float xc = xrow[t0 + u];
            const float Gi = fexp2(fmaf(xc, wi2, bi2));   // e^{pre_i}
            Gf[u]  = fexp2(fmaf(xc, wf2, bf2));           // e^{pre_f}
            Goa[u] = fexp2(fmaf(xc, wo2, bo2));           // 0.01*e^{pre_o}
            const float eg = fexp2(fmaf(xc, wg2, bg2));   // e^{-pre_g}
            const float Gg = frcp(fmaf(eg, -LN2, -LN2));  // -L2E*sigmoid(pre_g)
            GiGg[u] = Gi * Gg;
            const float el = fexp2(fmaf(xc, wl2, bl2));   // e^{-pre_l}
            Il[u]   = fmaf(frcp(el + 1.01f), -0.01f, 1.0f);
            Gs[u]   = fmaf(Goa[u], 100.0f, Gi + Gf[u]);
        }
    };

    // serial recurrence for one chunk (r3 math verbatim)
    auto rec = [&](int par, const float* Gf, const float* GiGg,
                   const float* Goa, const float* Gs, const float* Il) {
        float* __restrict__ hrow = &hlds[par * HBUF + tid * HSTR];
        #pragma unroll
        for (int u = 0; u < CH; ++u) {
            const float Enu = (u == 0) ? En : En * CUP[u];
            const float ef  = Gf[u] * Enu;
            C = fmaf(ef, C, GiGg[u] * Enu);              // C = -L2E*c
            const float sc = frcp(1.0f + fexp2(C));      // sigmoid(c)
            h = fmaf(Goa[u] * Enu, sc, h) * Il[u];
            hrow[u] = h;
            m = fmaf(Gs[u] * Enu, -KNU, m);
            if (u == CH - 1) m += CREB;
            En = fexp2(m);
        }
    };

    float GfA[CH], GiGgA[CH], GoaA[CH], GsA[CH], IlA[CH];
    float GfB[CH], GiGgB[CH], GoaB[CH], GsB[CH], IlB[CH];

    if (tid < TPB) gen(0, GfA, GiGgA, GoaA, GsA, IlA);   // prologue: chunk 0

    int par = 0;
    for (int ci = 0; ci < NCH; ci += 2) {
        // ---- even chunk: rec(A) co-scheduled with gen(B = chunk ci+1) ----
        if (tid < TPB) {
            gen((ci + 1) * CH, GfB, GiGgB, GoaB, GsB, IlB);  // independent
            rec(par, GfA, GiGgA, GoaA, GsA, IlA);            // serial chain
        }
        __syncthreads();
        if (tid >= TPB) {
            const float* __restrict__ hb = &hlds[par * HBUF];
            float sum = 0.0f;
            #pragma unroll
            for (int i2 = 0; i2 < 32; ++i2) {
                const int jj = rseg * 32 + ((i2 + 4 * rseg) & 31);
                sum = fmaf(hb[jj * HSTR + rt], pwreg[i2], sum);
            }
            sum += __shfl_xor(sum, 1, 64);
            sum += __shfl_xor(sum, 2, 64);
            sum += __shfl_xor(sum, 4, 64);
            if (rseg == 0) atomicAdd(&orow[(ci * CH + rt) * 2 + rk], sum);
        }
        par ^= 1;
        // ---- odd chunk: rec(B) co-scheduled with gen(A = chunk ci+2) ----
        if (tid < TPB) {
            if (ci + 2 < NCH) gen((ci + 2) * CH, GfA, GiGgA, GoaA, GsA, IlA);
            rec(par, GfB, GiGgB, GoaB, GsB, IlB);
        }
        __syncthreads();
        if (tid >= TPB) {
            const float* __restrict__ hb = &hlds[par * HBUF];
            float sum = 0.0f;
            #pragma unroll
            for (int i2 = 0; i2 < 32; ++i2) {
                const int jj = rseg * 32 + ((i2 + 4 * rseg) & 31);
                sum = fmaf(hb[jj * HSTR + rt], pwreg[i2], sum);
            }
            sum += __shfl_xor(sum, 1, 64);
            sum += __shfl_xor(sum, 2, 64);
            sum += __shfl_xor(sum, 4, 64);
            if (rseg == 0) atomicAdd(&orow[((ci + 1) * CH + rt) * 2 + rk], sum);
        }
        par ^= 1;
    }
}

extern "C" void kernel_launch(void* const* d_in, const int* in_sizes, int n_in,
                              void* d_out, int out_size, void* d_ws, size_t ws_size,
                              hipStream_t stream) {
    const float* x_codes = (const float*)d_in[0];
    const float* Wi_w = (const float*)d_in[1];
    const float* Wi_b = (const float*)d_in[2];
    const float* Wf_w = (const float*)d_in[3];
    const float* Wf_b = (const float*)d_in[4];
    const float* Wo_w = (const float*)d_in[5];
    const float* Wo_b = (const float*)d_in[6];
    const float* Wg_w = (const float*)d_in[7];
    const float* Wg_b = (const float*)d_in[8];
    const float* Wl_w = (const float*)d_in[9];
    const float* Wl_b = (const float*)d_in[10];
    const float* proj_w = (const float*)d_in[11];
    const float* proj_b = (const float*)d_in[12];
    const float* n_init = (const float*)d_in[13];
    float* out = (float*)d_out;

    init_out<<<out_size / 256, 256, 0, stream>>>(proj_b, out);
    cfc_scan<<<Bv * (Hv / TPB), NT, 0, stream>>>(
        x_codes, Wi_w, Wi_b, Wf_w, Wf_b, Wo_w, Wo_b, Wg_w, Wg_b, Wl_w, Wl_b,
        proj_w, n_init, out);
}